// Round 1
// baseline (253.316 us; speedup 1.0000x reference)
//
#include <hip/hip_runtime.h>

// HidePatchLayer: out = in * mask, mask[w,h] = (cell_rand[w/16, h/16] > 0.5)
// Shapes: in [256,224,224,3] f32, cell_rand [14,14] f32, grid_size = 16.
//
// Key structure: mask is constant over contiguous 48-float runs
// (fixed b,w,h-cell: 16 h x 3 c), and runs start at multiples of 48 floats,
// so every float4 lies entirely inside one run -> one mask lookup per float4,
// and hidden runs can skip the global load entirely (write exact zeros).
// Traffic: 154 MB write + ~77 MB read (~50% cells kept) ~= 231 MB -> ~35 us.
//
// R1 change: amortize the per-block prologue (cell_rand -> LDS + barrier).
// Previously 37,632 blocks x 4 KB each paid the prologue per 4 KB streamed.
// Now each block owns a contiguous 48 KB chunk (12 float4/thread, still
// perfectly coalesced per instruction), grid = 3,136 blocks -> prologue
// amortized 12x and cell_rand global re-reads cut 12x.

#define NCELL 196         // 14*14
#define BLOCK 256
#define ITER  12          // float4s per thread; BLOCK*ITER = 3072 float4/block

// Native clang vector type: __builtin_nontemporal_* rejects HIP_vector_type.
typedef float vfloat4 __attribute__((ext_vector_type(4)));

__global__ __launch_bounds__(BLOCK) void hide_patch_kernel(
    const vfloat4* __restrict__ in,
    const float*   __restrict__ cell_rand,
    vfloat4* __restrict__ out,
    unsigned n4)
{
    __shared__ float keep[NCELL];
    const unsigned t = threadIdx.x;
    if (t < NCELL) keep[t] = (cell_rand[t] > 0.5f) ? 1.0f : 0.0f;
    __syncthreads();

    unsigned i = blockIdx.x * (BLOCK * ITER) + t;
    #pragma unroll
    for (int k = 0; k < ITER; ++k, i += BLOCK) {
        if (i < n4) {
            // Cell of this float4 (all 4 elements share it; header comment).
            const unsigned base = i * 4u;
            const unsigned hw   = base / 3u;          // = b*224*224 + w*224 + h
            const unsigned h    = hw % 224u;
            const unsigned w    = (hw / 224u) % 224u; // W == H == 224
            const float m = keep[(w >> 4) * 14u + (h >> 4)];

            vfloat4 v = (vfloat4)(0.0f);
            if (m != 0.0f) {
                v = __builtin_nontemporal_load(&in[i]); // fetch only kept cells
            }
            __builtin_nontemporal_store(v, &out[i]);    // streaming store
        }
    }
}

extern "C" void kernel_launch(void* const* d_in, const int* in_sizes, int n_in,
                              void* d_out, int out_size, void* d_ws, size_t ws_size,
                              hipStream_t stream)
{
    const vfloat4* in        = (const vfloat4*)d_in[0]; // [256,224,224,3] f32
    const float*   cell_rand = (const float*)d_in[1];   // [14,14] f32
    // d_in[2] is grid_size (=16), baked into the shift constants above.

    vfloat4* out = (vfloat4*)d_out;

    const unsigned n  = (unsigned)in_sizes[0];          // 38,535,168 (div. by 4)
    const unsigned n4 = n / 4u;

    const unsigned per_block = BLOCK * ITER;            // 3072 float4
    const unsigned grid = (n4 + per_block - 1) / per_block;  // 3136 exactly
    hide_patch_kernel<<<grid, BLOCK, 0, stream>>>(in, cell_rand, out, n4);
}

// Round 2
// 250.484 us; speedup vs baseline: 1.0113x; 1.0113x over previous
//
#include <hip/hip_runtime.h>

// HidePatchLayer: out = in * mask, mask[w,h] = (cell_rand[w/16, h/16] > 0.5)
// Shapes: in [256,224,224,3] f32, cell_rand [14,14] f32, grid_size = 16.
//
// Key structure: mask is constant over contiguous 48-float runs
// (fixed b,w,h-cell: 16 h x 3 c), and runs start at multiples of 48 floats,
// so every float4 lies entirely inside one run -> one mask lookup per float4,
// and hidden runs can skip the global load entirely (write exact zeros).
// Traffic: 154 MB write + ~77 MB read (~50% cells kept) ~= 231 MB -> ~36 us
// at the 6.3 TB/s achievable ceiling.
//
// R1 post-mortem: chunked 12 float4/block-thread -> grid of 3,136 blocks =
// only 1.53 rounds of the 2,048 concurrently-resident blocks (8/CU x 256 CU)
// -> final-round drain idled ~1/3 of the machine; regressed ~5 us.
// R2: persistent grid-stride. Launch exactly 2,048 blocks (full residency,
// all blocks start at t=0, finish within ~1 of 18 iterations of each other
// -> tail ~5%), prologue paid 2,048x (negligible), per-iteration body is
// R0's proven 1-float4 structure. Stride covers a contiguous 8 MB span per
// iteration -> globally streaming access.

#define NCELL 196         // 14*14
#define BLOCK 256
#define GRID  2048        // 8 blocks/CU x 256 CU = full residency (32 waves/CU)

// Native clang vector type: __builtin_nontemporal_* rejects HIP_vector_type.
typedef float vfloat4 __attribute__((ext_vector_type(4)));

__global__ __launch_bounds__(BLOCK) void hide_patch_kernel(
    const vfloat4* __restrict__ in,
    const float*   __restrict__ cell_rand,
    vfloat4* __restrict__ out,
    unsigned n4)
{
    __shared__ float keep[NCELL];
    const unsigned t = threadIdx.x;
    if (t < NCELL) keep[t] = (cell_rand[t] > 0.5f) ? 1.0f : 0.0f;
    __syncthreads();

    const unsigned stride = GRID * BLOCK;               // 524,288 float4 = 8 MB
    for (unsigned i = blockIdx.x * BLOCK + t; i < n4; i += stride) {
        // Cell of this float4 (all 4 elements share it; see header comment).
        const unsigned base = i * 4u;
        const unsigned hw   = base / 3u;            // = b*224*224 + w*224 + h
        const unsigned h    = hw % 224u;
        const unsigned w    = (hw / 224u) % 224u;   // W == H == 224
        const float m = keep[(w >> 4) * 14u + (h >> 4)];

        vfloat4 v = (vfloat4)(0.0f);
        if (m != 0.0f) {
            v = __builtin_nontemporal_load(&in[i]);  // fetch only kept cells
        }
        __builtin_nontemporal_store(v, &out[i]);     // streaming store, no reuse
    }
}

extern "C" void kernel_launch(void* const* d_in, const int* in_sizes, int n_in,
                              void* d_out, int out_size, void* d_ws, size_t ws_size,
                              hipStream_t stream)
{
    const vfloat4* in        = (const vfloat4*)d_in[0]; // [256,224,224,3] f32
    const float*   cell_rand = (const float*)d_in[1];   // [14,14] f32
    // d_in[2] is grid_size (=16), baked into the shift constants above.

    vfloat4* out = (vfloat4*)d_out;

    const unsigned n  = (unsigned)in_sizes[0];          // 38,535,168 (div. by 4)
    const unsigned n4 = n / 4u;                         // 9,633,792

    // ~18.4 iterations/thread at GRID=2048; never launch more blocks than work.
    const unsigned blocks_needed = (n4 + BLOCK - 1) / BLOCK;
    const unsigned grid = blocks_needed < GRID ? blocks_needed : GRID;
    hide_patch_kernel<<<grid, BLOCK, 0, stream>>>(in, cell_rand, out, n4);
}

// Round 3
// 249.410 us; speedup vs baseline: 1.0157x; 1.0043x over previous
//
#include <hip/hip_runtime.h>

// HidePatchLayer: out = in * mask, mask[w,h] = (cell_rand[w/16, h/16] > 0.5)
// Shapes: in [256,224,224,3] f32, cell_rand [14,14] f32, grid_size = 16.
//
// Mask is constant over contiguous 48-float runs (16 h x 3 c), runs start at
// multiples of 48 floats -> every float4 lies in one run -> one mask lookup
// per float4; hidden runs skip the global load (write exact zeros).
// Traffic: 154 MB write + ~77 MB read (~50% kept) ~= 231 MB -> ~37 us ideal.
//
// R1: 12-float4 chunked blocks -> 1.53 scheduling rounds, tail drain, -5 us. BAD
// R2: persistent 2048-block grid-stride -> fixed tail, but no net win vs R0.
// R3 theory: loop body was load -> waitcnt -> store (1 outstanding load/wave,
// serialized against ~900 cy HBM latency). Unroll x4 across stride-8MB
// offsets: 4 independent load chains issued back-to-back -> 4x MLP, 4x less
// loop overhead. Grid/residency unchanged (2048 blocks, 32 waves/CU).

#define NCELL 196         // 14*14
#define BLOCK 256
#define GRID  2048        // 8 blocks/CU x 256 CU = full residency
#define UNROLL 4

// Native clang vector type: __builtin_nontemporal_* rejects HIP_vector_type.
typedef float vfloat4 __attribute__((ext_vector_type(4)));

__device__ __forceinline__ float mask_of(unsigned i, const float* keep)
{
    const unsigned base = i * 4u;
    const unsigned hw   = base / 3u;            // = b*224*224 + w*224 + h
    const unsigned h    = hw % 224u;
    const unsigned w    = (hw / 224u) % 224u;   // W == H == 224
    return keep[(w >> 4) * 14u + (h >> 4)];
}

__global__ __launch_bounds__(BLOCK) void hide_patch_kernel(
    const vfloat4* __restrict__ in,
    const float*   __restrict__ cell_rand,
    vfloat4* __restrict__ out,
    unsigned n4)
{
    __shared__ float keep[NCELL];
    const unsigned t = threadIdx.x;
    if (t < NCELL) keep[t] = (cell_rand[t] > 0.5f) ? 1.0f : 0.0f;
    __syncthreads();

    const unsigned S = GRID * BLOCK;            // 524,288 float4 = 8 MB
    unsigned i = blockIdx.x * BLOCK + t;

    // Main: 4 independent float4 streams, 8 MB apart. Loads issued first
    // (no cross-dependencies) -> 4 outstanding global_load_dwordx4 per wave.
    while (i + 3u * S < n4) {
        const unsigned i0 = i, i1 = i + S, i2 = i + 2u * S, i3 = i + 3u * S;

        const float m0 = mask_of(i0, keep);
        const float m1 = mask_of(i1, keep);
        const float m2 = mask_of(i2, keep);
        const float m3 = mask_of(i3, keep);

        vfloat4 v0 = (vfloat4)(0.0f), v1 = (vfloat4)(0.0f);
        vfloat4 v2 = (vfloat4)(0.0f), v3 = (vfloat4)(0.0f);
        if (m0 != 0.0f) v0 = __builtin_nontemporal_load(&in[i0]);
        if (m1 != 0.0f) v1 = __builtin_nontemporal_load(&in[i1]);
        if (m2 != 0.0f) v2 = __builtin_nontemporal_load(&in[i2]);
        if (m3 != 0.0f) v3 = __builtin_nontemporal_load(&in[i3]);

        __builtin_nontemporal_store(v0, &out[i0]);
        __builtin_nontemporal_store(v1, &out[i1]);
        __builtin_nontemporal_store(v2, &out[i2]);
        __builtin_nontemporal_store(v3, &out[i3]);

        i += (unsigned)UNROLL * S;
    }

    // Tail: remaining 0-3 stride-steps (spread evenly across all blocks).
    for (; i < n4; i += S) {
        const float m = mask_of(i, keep);
        vfloat4 v = (vfloat4)(0.0f);
        if (m != 0.0f) v = __builtin_nontemporal_load(&in[i]);
        __builtin_nontemporal_store(v, &out[i]);
    }
}

extern "C" void kernel_launch(void* const* d_in, const int* in_sizes, int n_in,
                              void* d_out, int out_size, void* d_ws, size_t ws_size,
                              hipStream_t stream)
{
    const vfloat4* in        = (const vfloat4*)d_in[0]; // [256,224,224,3] f32
    const float*   cell_rand = (const float*)d_in[1];   // [14,14] f32
    // d_in[2] is grid_size (=16), baked into the shift constants above.

    vfloat4* out = (vfloat4*)d_out;

    const unsigned n  = (unsigned)in_sizes[0];          // 38,535,168 (div. by 4)
    const unsigned n4 = n / 4u;                         // 9,633,792

    const unsigned blocks_needed = (n4 + BLOCK - 1) / BLOCK;
    const unsigned grid = blocks_needed < GRID ? blocks_needed : GRID;
    hide_patch_kernel<<<grid, BLOCK, 0, stream>>>(in, cell_rand, out, n4);
}